// Round 1
// baseline (2066.838 us; speedup 1.0000x reference)
//
#include <hip/hip_runtime.h>
#include <hip/hip_bf16.h>

#define T_TOKENS 16384
#define HID 1024
#define NEXP 8
#define INTER 3584

using f32x4   = __attribute__((ext_vector_type(4))) float;
using bfrag   = __attribute__((ext_vector_type(8))) short;
using short4_t = __attribute__((ext_vector_type(4))) short;
using float4_t = __attribute__((ext_vector_type(4))) float;

__device__ inline unsigned short f2bf(float f){
    unsigned u = __float_as_uint(f);
    u += 0x7FFFu + ((u >> 16) & 1u);          // round-to-nearest-even
    return (unsigned short)(u >> 16);
}

__device__ inline short4_t f4_to_bf4(float4_t v){
    short4_t s;
    s.x = (short)f2bf(v.x);
    s.y = (short)f2bf(v.y);
    s.z = (short)f2bf(v.z);
    s.w = (short)f2bf(v.w);
    return s;
}

// ---------------- router: logits -> top2 -> renorm weights ----------------
__global__ __launch_bounds__(256) void router_kernel(
    const float* __restrict__ x, const float* __restrict__ gw,
    int* __restrict__ topk_idx, float* __restrict__ topk_w,
    int* __restrict__ counts)
{
    int wave = threadIdx.x >> 6;
    int lane = threadIdx.x & 63;
    int t = blockIdx.x * 4 + wave;

    float acc[NEXP];
#pragma unroll
    for (int e = 0; e < NEXP; ++e) acc[e] = 0.f;

    const float* xr = x + (size_t)t * HID;
    for (int hb = 0; hb < HID; hb += 64){
        float xv = xr[hb + lane];
#pragma unroll
        for (int e = 0; e < NEXP; ++e)
            acc[e] += xv * gw[e * HID + hb + lane];
    }
#pragma unroll
    for (int e = 0; e < NEXP; ++e){
#pragma unroll
        for (int s = 32; s > 0; s >>= 1)
            acc[e] += __shfl_xor(acc[e], s, 64);
    }
    if (lane == 0){
        int e0 = 0; float m0 = acc[0];
#pragma unroll
        for (int e = 1; e < NEXP; ++e) if (acc[e] > m0){ m0 = acc[e]; e0 = e; }
        int e1 = -1; float m1 = -1e30f;
#pragma unroll
        for (int e = 0; e < NEXP; ++e) if (e != e0 && acc[e] > m1){ m1 = acc[e]; e1 = e; }
        // renormalized top-2 softmax weights: ratio of exps
        float p1 = __expf(m1 - m0);
        float inv = 1.f / (1.f + p1);
        topk_idx[2*t]   = e0;
        topk_idx[2*t+1] = e1;
        topk_w[2*t]   = inv;
        topk_w[2*t+1] = p1 * inv;
        atomicAdd(&counts[e0], 1);
        atomicAdd(&counts[e1], 1);
    }
}

// ---------------- tiny prefix scan over 8 counts ----------------
__global__ void scan_kernel(const int* __restrict__ counts, int* __restrict__ offsets)
{
    if (threadIdx.x == 0 && blockIdx.x == 0){
        int s = 0;
        for (int e = 0; e < NEXP; ++e){ offsets[e] = s; s += counts[e]; }
        offsets[NEXP] = s;
    }
}

// ---------------- scatter tokens into per-expert compact lists ----------------
__global__ __launch_bounds__(256) void scatter_kernel(
    const int* __restrict__ topk_idx, const float* __restrict__ topk_w,
    const int* __restrict__ offsets, int* __restrict__ cursors,
    int* __restrict__ pair_token, float* __restrict__ pair_w)
{
    int t = blockIdx.x * 256 + threadIdx.x;
#pragma unroll
    for (int k = 0; k < 2; ++k){
        int e = topk_idx[2*t + k];
        int slot = atomicAdd(&cursors[e], 1);
        int p = offsets[e] + slot;
        pair_token[p] = t;
        pair_w[p] = topk_w[2*t + k];
    }
}

// ---------------- fused w1/w3 GEMM + SwiGLU -> act (bf16) ----------------
// tile: 128 rows (pairs) x 64 cols (INTER chunk), K = HID, BK = 32
__global__ __launch_bounds__(256) void gemm_act_kernel(
    const float* __restrict__ x, const float* __restrict__ w1,
    const float* __restrict__ w3,
    const int* __restrict__ counts, const int* __restrict__ offsets,
    const int* __restrict__ pair_token, const float* __restrict__ pair_w,
    unsigned short* __restrict__ act, int chunk_base, int ci)
{
    int e = blockIdx.z;
    int cnt = counts[e];
    int row0 = blockIdx.y * 128;
    if (row0 >= cnt) return;
    int off = offsets[e];
    int icol0 = chunk_base + blockIdx.x * 64;   // global INTER col base

    __shared__ short As[128][32];
    __shared__ short Bs1[64][32];
    __shared__ short Bs3[64][32];
    __shared__ int   toks[128];
    __shared__ float pws[128];

    int tid = threadIdx.x;
    if (tid < 128){
        int r = row0 + tid;
        int rc = (r < cnt) ? r : (cnt - 1);
        toks[tid] = pair_token[off + rc];
        pws[tid]  = pair_w[off + rc];
    }
    __syncthreads();

    // hoist per-thread A row bases (same rows every K-step)
    size_t arow[4];
#pragma unroll
    for (int it = 0; it < 4; ++it)
        arow[it] = (size_t)toks[(tid >> 3) + it * 32] * HID;

    int wave = tid >> 6, lane = tid & 63;
    int wm = wave >> 1, wn = wave & 1;

    f32x4 acc_h[4][2], acc_u[4][2];
#pragma unroll
    for (int m = 0; m < 4; ++m)
#pragma unroll
        for (int n = 0; n < 2; ++n){
            acc_h[m][n] = (f32x4){0.f,0.f,0.f,0.f};
            acc_u[m][n] = (f32x4){0.f,0.f,0.f,0.f};
        }

    const float* w1e = w1 + (size_t)e * INTER * HID;
    const float* w3e = w3 + (size_t)e * INTER * HID;

    for (int k0 = 0; k0 < HID; k0 += 32){
        __syncthreads();
        // stage A (gathered token rows), f32 -> bf16
#pragma unroll
        for (int it = 0; it < 4; ++it){
            int r  = (tid >> 3) + it * 32;
            int c4 = (tid & 7) * 4;
            float4_t v = *reinterpret_cast<const float4_t*>(x + arow[it] + k0 + c4);
            *reinterpret_cast<short4_t*>(&As[r][c4]) = f4_to_bf4(v);
        }
        // stage B1/B3 (w1/w3 rows = INTER dim), f32 -> bf16
#pragma unroll
        for (int it = 0; it < 2; ++it){
            int f4 = tid + it * 256;
            int r  = f4 >> 3;
            int c4 = (f4 & 7) * 4;
            float4_t v1 = *reinterpret_cast<const float4_t*>(w1e + (size_t)(icol0 + r) * HID + k0 + c4);
            *reinterpret_cast<short4_t*>(&Bs1[r][c4]) = f4_to_bf4(v1);
            float4_t v3 = *reinterpret_cast<const float4_t*>(w3e + (size_t)(icol0 + r) * HID + k0 + c4);
            *reinterpret_cast<short4_t*>(&Bs3[r][c4]) = f4_to_bf4(v3);
        }
        __syncthreads();

        bfrag a[4];
#pragma unroll
        for (int m = 0; m < 4; ++m)
            a[m] = *reinterpret_cast<const bfrag*>(&As[wm*64 + m*16 + (lane & 15)][(lane >> 4) * 8]);
#pragma unroll
        for (int n = 0; n < 2; ++n){
            bfrag b1 = *reinterpret_cast<const bfrag*>(&Bs1[wn*32 + n*16 + (lane & 15)][(lane >> 4) * 8]);
            bfrag b3 = *reinterpret_cast<const bfrag*>(&Bs3[wn*32 + n*16 + (lane & 15)][(lane >> 4) * 8]);
#pragma unroll
            for (int m = 0; m < 4; ++m){
                acc_h[m][n] = __builtin_amdgcn_mfma_f32_16x16x32_bf16(a[m], b1, acc_h[m][n], 0, 0, 0);
                acc_u[m][n] = __builtin_amdgcn_mfma_f32_16x16x32_bf16(a[m], b3, acc_u[m][n], 0, 0, 0);
            }
        }
    }

    // epilogue: act = pair_w * silu(h) * u  (bf16)
#pragma unroll
    for (int m = 0; m < 4; ++m){
#pragma unroll
        for (int n = 0; n < 2; ++n){
#pragma unroll
            for (int j = 0; j < 4; ++j){
                int rl = wm*64 + m*16 + (lane >> 4) * 4 + j;
                int r  = row0 + rl;
                if (r < cnt){
                    float h = acc_h[m][n][j];
                    float u = acc_u[m][n][j];
                    float sig = 1.f / (1.f + __expf(-h));
                    float v = pws[rl] * h * sig * u;
                    int cl = blockIdx.x * 64 + wn*32 + n*16 + (lane & 15);
                    act[(size_t)(off + r) * ci + cl] = f2bf(v);
                }
            }
        }
    }
}

// ---------------- down-proj GEMM: out[t,:] += act[p,:] @ w2[e]^T ----------------
// tile: 128 rows (pairs) x 64 cols (HID), K = ci chunk, BK = 32
__global__ __launch_bounds__(256) void gemm2_kernel(
    const unsigned short* __restrict__ act, const float* __restrict__ w2,
    const int* __restrict__ counts, const int* __restrict__ offsets,
    const int* __restrict__ pair_token,
    float* __restrict__ out, int chunk_base, int ci)
{
    int e = blockIdx.z;
    int cnt = counts[e];
    int row0 = blockIdx.y * 128;
    if (row0 >= cnt) return;
    int off = offsets[e];
    int h0 = blockIdx.x * 64;

    __shared__ short As[128][32];
    __shared__ short Bs[64][32];
    __shared__ int   toks[128];

    int tid = threadIdx.x;
    if (tid < 128){
        int r = row0 + tid;
        toks[tid] = pair_token[off + ((r < cnt) ? r : (cnt - 1))];
    }
    __syncthreads();

    // hoist clamped A rows for staging (2 x 16B per thread per K-step)
    size_t arowb[2];
#pragma unroll
    for (int it = 0; it < 2; ++it){
        int idx = tid + it * 256;
        int r = idx >> 2;
        int rc = row0 + r; rc = (rc < cnt) ? rc : (cnt - 1);
        arowb[it] = (size_t)(off + rc) * ci;
    }

    int wave = tid >> 6, lane = tid & 63;
    int wm = wave >> 1, wn = wave & 1;

    f32x4 acc[4][2];
#pragma unroll
    for (int m = 0; m < 4; ++m)
#pragma unroll
        for (int n = 0; n < 2; ++n)
            acc[m][n] = (f32x4){0.f,0.f,0.f,0.f};

    const float* w2e = w2 + (size_t)e * HID * INTER;

    for (int kc = 0; kc < ci; kc += 32){
        __syncthreads();
        // stage A: act rows are already bf16 — raw 16B copies
#pragma unroll
        for (int it = 0; it < 2; ++it){
            int idx = tid + it * 256;
            int r  = idx >> 2;
            int c8 = (idx & 3) * 8;
            float4_t v = *reinterpret_cast<const float4_t*>(act + arowb[it] + kc + c8);
            *reinterpret_cast<float4_t*>(&As[r][c8]) = v;
        }
        // stage B: w2 rows (HID dim) x K (INTER chunk), f32 -> bf16
#pragma unroll
        for (int it = 0; it < 2; ++it){
            int f4 = tid + it * 256;
            int r  = f4 >> 3;
            int c4 = (f4 & 7) * 4;
            float4_t v = *reinterpret_cast<const float4_t*>(
                w2e + (size_t)(h0 + r) * INTER + chunk_base + kc + c4);
            *reinterpret_cast<short4_t*>(&Bs[r][c4]) = f4_to_bf4(v);
        }
        __syncthreads();

        bfrag a[4];
#pragma unroll
        for (int m = 0; m < 4; ++m)
            a[m] = *reinterpret_cast<const bfrag*>(&As[wm*64 + m*16 + (lane & 15)][(lane >> 4) * 8]);
#pragma unroll
        for (int n = 0; n < 2; ++n){
            bfrag b = *reinterpret_cast<const bfrag*>(&Bs[wn*32 + n*16 + (lane & 15)][(lane >> 4) * 8]);
#pragma unroll
            for (int m = 0; m < 4; ++m)
                acc[m][n] = __builtin_amdgcn_mfma_f32_16x16x32_bf16(a[m], b, acc[m][n], 0, 0, 0);
        }
    }

    // epilogue: atomic accumulate into out (weight already folded into act)
#pragma unroll
    for (int m = 0; m < 4; ++m){
#pragma unroll
        for (int n = 0; n < 2; ++n){
#pragma unroll
            for (int j = 0; j < 4; ++j){
                int rl = wm*64 + m*16 + (lane >> 4) * 4 + j;
                int r  = row0 + rl;
                if (r < cnt){
                    int t  = toks[rl];
                    int hc = h0 + wn*32 + n*16 + (lane & 15);
                    atomicAdd(&out[(size_t)t * HID + hc], acc[m][n][j]);
                }
            }
        }
    }
}

extern "C" void kernel_launch(void* const* d_in, const int* in_sizes, int n_in,
                              void* d_out, int out_size, void* d_ws, size_t ws_size,
                              hipStream_t stream)
{
    const float* x  = (const float*)d_in[0];
    const float* gw = (const float*)d_in[1];
    const float* w1 = (const float*)d_in[2];
    const float* w3 = (const float*)d_in[3];
    const float* w2 = (const float*)d_in[4];
    float* out = (float*)d_out;

    char* ws = (char*)d_ws;
    int*   counts     = (int*)ws;                                  // 8
    int*   cursors    = (int*)(ws + 32);                           // 8
    int*   offsets    = (int*)(ws + 64);                           // 9
    int*   topk_idx   = (int*)(ws + 256);                          // 2T
    float* topk_w     = (float*)(ws + 256 + 2*T_TOKENS*4);         // 2T
    int*   pair_token = (int*)(ws + 256 + 4*T_TOKENS*4);           // 2T
    float* pair_w     = (float*)(ws + 256 + 6*T_TOKENS*4);         // 2T
    size_t fixed = 256 + 8*(size_t)T_TOKENS*4 + 256;
    unsigned short* act = (unsigned short*)(ws + fixed);

    // pick the biggest act chunk that fits in ws
    static const int chunk_opts[] = {1, 2, 4, 7, 8, 14, 16, 28, 56};
    int nchunks = 56;
    for (int i = 0; i < 9; ++i){
        size_t ci_try = INTER / chunk_opts[i];
        if (fixed + (size_t)2 * T_TOKENS * ci_try * 2 <= ws_size){
            nchunks = chunk_opts[i];
            break;
        }
    }
    int ci = INTER / nchunks;

    hipMemsetAsync(d_out, 0, (size_t)T_TOKENS * HID * 4, stream);
    hipMemsetAsync(ws, 0, 64, stream);

    router_kernel<<<T_TOKENS/4, 256, 0, stream>>>(x, gw, topk_idx, topk_w, counts);
    scan_kernel<<<1, 64, 0, stream>>>(counts, offsets);
    scatter_kernel<<<T_TOKENS/256, 256, 0, stream>>>(topk_idx, topk_w, offsets, cursors,
                                                     pair_token, pair_w);
    for (int c = 0; c < nchunks; ++c){
        int cb = c * ci;
        gemm_act_kernel<<<dim3(ci/64, T_TOKENS/128, NEXP), 256, 0, stream>>>(
            x, w1, w3, counts, offsets, pair_token, pair_w, act, cb, ci);
        gemm2_kernel<<<dim3(HID/64, T_TOKENS/128, NEXP), 256, 0, stream>>>(
            act, w2, counts, offsets, pair_token, out, cb, ci);
    }
}

// Round 2
// 1941.526 us; speedup vs baseline: 1.0645x; 1.0645x over previous
//
#include <hip/hip_runtime.h>
#include <hip/hip_bf16.h>

#define T_TOKENS 16384
#define HID 1024
#define NEXP 8
#define INTER 3584
#define PAIRS (2*T_TOKENS)
#define PAD_MAX (PAIRS + NEXP*128)   // 33792, multiple of 128

using f32x4    = __attribute__((ext_vector_type(4))) float;
using bfrag    = __attribute__((ext_vector_type(8))) short;
using float4_t = __attribute__((ext_vector_type(4))) float;
using ushort8_t = __attribute__((ext_vector_type(8))) unsigned short;

__device__ inline unsigned short f2bf(float f){
    unsigned u = __float_as_uint(f);
    u += 0x7FFFu + ((u >> 16) & 1u);          // RNE
    return (unsigned short)(u >> 16);
}

// async global -> LDS, 16B per lane, dest = ldsbase + lane*16
__device__ inline void gload16(const unsigned short* g, unsigned short* l){
    __builtin_amdgcn_global_load_lds(
        (const __attribute__((address_space(1))) void*)g,
        (__attribute__((address_space(3))) void*)l, 16, 0, 0);
}

// ---------------- f32 -> bf16 bulk conversion ----------------
__global__ __launch_bounds__(256) void conv_bf16_kernel(
    const float* __restrict__ in, unsigned short* __restrict__ out, int n)
{
    int i0 = (blockIdx.x * 256 + threadIdx.x) * 8;
    int stride = gridDim.x * 256 * 8;
    for (int i = i0; i < n; i += stride){
        float4_t a = *reinterpret_cast<const float4_t*>(in + i);
        float4_t b = *reinterpret_cast<const float4_t*>(in + i + 4);
        ushort8_t o;
        o[0]=f2bf(a.x); o[1]=f2bf(a.y); o[2]=f2bf(a.z); o[3]=f2bf(a.w);
        o[4]=f2bf(b.x); o[5]=f2bf(b.y); o[6]=f2bf(b.z); o[7]=f2bf(b.w);
        *reinterpret_cast<ushort8_t*>(out + i) = o;
    }
}

// ---------------- router: logits -> top2 -> renorm weights ----------------
__global__ __launch_bounds__(256) void router_kernel(
    const float* __restrict__ x, const float* __restrict__ gw,
    int* __restrict__ topk_idx, float* __restrict__ topk_w,
    int* __restrict__ counts)
{
    int wave = threadIdx.x >> 6;
    int lane = threadIdx.x & 63;
    int t = blockIdx.x * 4 + wave;

    float acc[NEXP];
#pragma unroll
    for (int e = 0; e < NEXP; ++e) acc[e] = 0.f;

    const float* xr = x + (size_t)t * HID;
    for (int hb = 0; hb < HID; hb += 64){
        float xv = xr[hb + lane];
#pragma unroll
        for (int e = 0; e < NEXP; ++e)
            acc[e] += xv * gw[e * HID + hb + lane];
    }
#pragma unroll
    for (int e = 0; e < NEXP; ++e){
#pragma unroll
        for (int s = 32; s > 0; s >>= 1)
            acc[e] += __shfl_xor(acc[e], s, 64);
    }
    if (lane == 0){
        int e0 = 0; float m0 = acc[0];
#pragma unroll
        for (int e = 1; e < NEXP; ++e) if (acc[e] > m0){ m0 = acc[e]; e0 = e; }
        int e1 = -1; float m1 = -1e30f;
#pragma unroll
        for (int e = 0; e < NEXP; ++e) if (e != e0 && acc[e] > m1){ m1 = acc[e]; e1 = e; }
        float p1 = __expf(m1 - m0);
        float inv = 1.f / (1.f + p1);
        topk_idx[2*t]   = e0;
        topk_idx[2*t+1] = e1;
        topk_w[2*t]   = inv;
        topk_w[2*t+1] = p1 * inv;
        atomicAdd(&counts[e0], 1);
        atomicAdd(&counts[e1], 1);
    }
}

// ---------------- prefix scan with 128-row padding per expert ----------------
__global__ void scan_kernel(const int* __restrict__ counts, int* __restrict__ offp)
{
    if (threadIdx.x == 0 && blockIdx.x == 0){
        int s = 0;
        for (int e = 0; e < NEXP; ++e){
            offp[e] = s;
            s += (counts[e] + 127) & ~127;
        }
        offp[NEXP] = s;
    }
}

// fill pad rows: weight 0, distinct dummy tokens (zero contribution, no hotspot)
__global__ __launch_bounds__(128) void padfill_kernel(
    const int* __restrict__ counts, const int* __restrict__ offp,
    int* __restrict__ pair_token, float* __restrict__ pair_w)
{
    int e = blockIdx.x;
    int base = offp[e];
    int aligned = offp[e+1] - base;
    for (int s = counts[e] + threadIdx.x; s < aligned; s += 128){
        pair_token[base + s] = (base + s) & (T_TOKENS - 1);
        pair_w[base + s] = 0.f;
    }
}

// ---------------- scatter tokens into per-expert compact (padded) lists ----------------
__global__ __launch_bounds__(256) void scatter_kernel(
    const int* __restrict__ topk_idx, const float* __restrict__ topk_w,
    const int* __restrict__ offp, int* __restrict__ cursors,
    int* __restrict__ pair_token, float* __restrict__ pair_w)
{
    int t = blockIdx.x * 256 + threadIdx.x;
#pragma unroll
    for (int k = 0; k < 2; ++k){
        int e = topk_idx[2*t + k];
        int slot = atomicAdd(&cursors[e], 1);
        int p = offp[e] + slot;
        pair_token[p] = t;
        pair_w[p] = topk_w[2*t + k];
    }
}

// ---------------- fused w1/w3 GEMM + SwiGLU -> act (bf16) ----------------
// M-tile 128 pair rows x N-tile 64 INTER cols (both h and u), BK = 64, K = HID
__global__ __launch_bounds__(256) void gemm_act_kernel(
    const unsigned short* __restrict__ xb,
    const unsigned short* __restrict__ w1b,
    const unsigned short* __restrict__ w3b,
    const int* __restrict__ offp,
    const int* __restrict__ pair_token, const float* __restrict__ pair_w,
    unsigned short* __restrict__ act, int r0)
{
    int R = r0 + blockIdx.y * 128;        // global (padded) pair row base
    if (R >= offp[NEXP]) return;
    int e = 0;
    while (offp[e+1] <= R) ++e;
    int icol0 = blockIdx.x * 64;

    __shared__ alignas(16) unsigned short As[128*64];
    __shared__ alignas(16) unsigned short B1s[64*64];
    __shared__ alignas(16) unsigned short B3s[64*64];
    __shared__ int   toks[128];
    __shared__ float pws[128];

    int tid = threadIdx.x;
    if (tid < 128){
        toks[tid] = pair_token[R + tid];
        pws[tid]  = pair_w[R + tid];
    }
    __syncthreads();

    int w = tid >> 6, lane = tid & 63;
    int wm = w >> 1, wn = w & 1;
    int lr = lane >> 3, lc8 = (lane & 7) * 8;

    // per-lane gather sources for A (token rows), hoisted
    size_t asrc[4];
#pragma unroll
    for (int i = 0; i < 4; ++i)
        asrc[i] = (size_t)toks[w*32 + i*8 + lr] * HID + lc8;

    const unsigned short* w1e = w1b + (size_t)e * INTER * HID;
    const unsigned short* w3e = w3b + (size_t)e * INTER * HID;
    size_t bsrc[2];
#pragma unroll
    for (int i = 0; i < 2; ++i)
        bsrc[i] = (size_t)(icol0 + w*16 + i*8 + lr) * HID + lc8;

    f32x4 acc_h[4][2], acc_u[4][2];
#pragma unroll
    for (int m = 0; m < 4; ++m)
#pragma unroll
        for (int n = 0; n < 2; ++n){
            acc_h[m][n] = (f32x4){0.f,0.f,0.f,0.f};
            acc_u[m][n] = (f32x4){0.f,0.f,0.f,0.f};
        }

    for (int k0 = 0; k0 < HID; k0 += 64){
        __syncthreads();
#pragma unroll
        for (int i = 0; i < 4; ++i)
            gload16(xb + asrc[i] + k0, &As[(w*32 + i*8) * 64]);
#pragma unroll
        for (int i = 0; i < 2; ++i)
            gload16(w1e + bsrc[i] + k0, &B1s[(w*16 + i*8) * 64]);
#pragma unroll
        for (int i = 0; i < 2; ++i)
            gload16(w3e + bsrc[i] + k0, &B3s[(w*16 + i*8) * 64]);
        __syncthreads();

#pragma unroll
        for (int kk = 0; kk < 2; ++kk){
            bfrag a[4];
#pragma unroll
            for (int m = 0; m < 4; ++m)
                a[m] = *reinterpret_cast<const bfrag*>(
                    &As[(wm*64 + m*16 + (lane & 15)) * 64 + kk*32 + (lane >> 4) * 8]);
#pragma unroll
            for (int n = 0; n < 2; ++n){
                bfrag b1 = *reinterpret_cast<const bfrag*>(
                    &B1s[(wn*32 + n*16 + (lane & 15)) * 64 + kk*32 + (lane >> 4) * 8]);
                bfrag b3 = *reinterpret_cast<const bfrag*>(
                    &B3s[(wn*32 + n*16 + (lane & 15)) * 64 + kk*32 + (lane >> 4) * 8]);
#pragma unroll
                for (int m = 0; m < 4; ++m){
                    acc_h[m][n] = __builtin_amdgcn_mfma_f32_16x16x32_bf16(a[m], b1, acc_h[m][n], 0, 0, 0);
                    acc_u[m][n] = __builtin_amdgcn_mfma_f32_16x16x32_bf16(a[m], b3, acc_u[m][n], 0, 0, 0);
                }
            }
        }
    }

    // epilogue: act = pair_w * silu(h) * u  (bf16); pad rows have w==0 -> exact 0
    size_t arow0 = (size_t)(blockIdx.y * 128) * INTER;
#pragma unroll
    for (int m = 0; m < 4; ++m){
#pragma unroll
        for (int n = 0; n < 2; ++n){
#pragma unroll
            for (int j = 0; j < 4; ++j){
                int rl = wm*64 + m*16 + (lane >> 4)*4 + j;
                float h = acc_h[m][n][j];
                float u = acc_u[m][n][j];
                float v = pws[rl] * h * u / (1.f + __expf(-h));
                int ic = icol0 + wn*32 + n*16 + (lane & 15);
                act[arow0 + (size_t)rl * INTER + ic] = f2bf(v);
            }
        }
    }
}

// ---------------- down-proj GEMM: out[tok,:] += act[row,:] @ w2[e]^T ----------------
// M-tile 128 pair rows x N-tile 128 HID cols, BK = 64, K = INTER (full)
__global__ __launch_bounds__(256) void gemm2_kernel(
    const unsigned short* __restrict__ act,
    const unsigned short* __restrict__ w2b,
    const int* __restrict__ offp,
    const int* __restrict__ pair_token,
    float* __restrict__ out, int r0)
{
    int R = r0 + blockIdx.y * 128;
    if (R >= offp[NEXP]) return;
    int e = 0;
    while (offp[e+1] <= R) ++e;
    int h0 = blockIdx.x * 128;

    __shared__ alignas(16) unsigned short As[128*64];
    __shared__ alignas(16) unsigned short Bs[128*64];
    __shared__ int toks[128];

    int tid = threadIdx.x;
    if (tid < 128) toks[tid] = pair_token[R + tid];
    __syncthreads();

    int w = tid >> 6, lane = tid & 63;
    int wm = w >> 1, wn = w & 1;
    int lr = lane >> 3, lc8 = (lane & 7) * 8;

    const unsigned short* w2e = w2b + (size_t)e * HID * INTER;
    size_t arow0 = (size_t)(blockIdx.y * 128) * INTER;

    size_t asrc[4], bsrc[4];
#pragma unroll
    for (int i = 0; i < 4; ++i){
        asrc[i] = arow0 + (size_t)(w*32 + i*8 + lr) * INTER + lc8;
        bsrc[i] = (size_t)(h0 + w*32 + i*8 + lr) * INTER + lc8;
    }

    f32x4 acc[4][4];
#pragma unroll
    for (int m = 0; m < 4; ++m)
#pragma unroll
        for (int n = 0; n < 4; ++n)
            acc[m][n] = (f32x4){0.f,0.f,0.f,0.f};

    for (int kc = 0; kc < INTER; kc += 64){
        __syncthreads();
#pragma unroll
        for (int i = 0; i < 4; ++i)
            gload16(act + asrc[i] + kc, &As[(w*32 + i*8) * 64]);
#pragma unroll
        for (int i = 0; i < 4; ++i)
            gload16(w2e + bsrc[i] + kc, &Bs[(w*32 + i*8) * 64]);
        __syncthreads();

#pragma unroll
        for (int kk = 0; kk < 2; ++kk){
            bfrag a[4];
#pragma unroll
            for (int m = 0; m < 4; ++m)
                a[m] = *reinterpret_cast<const bfrag*>(
                    &As[(wm*64 + m*16 + (lane & 15)) * 64 + kk*32 + (lane >> 4) * 8]);
#pragma unroll
            for (int n = 0; n < 4; ++n){
                bfrag b = *reinterpret_cast<const bfrag*>(
                    &Bs[(wn*64 + n*16 + (lane & 15)) * 64 + kk*32 + (lane >> 4) * 8]);
#pragma unroll
                for (int m = 0; m < 4; ++m)
                    acc[m][n] = __builtin_amdgcn_mfma_f32_16x16x32_bf16(a[m], b, acc[m][n], 0, 0, 0);
            }
        }
    }

#pragma unroll
    for (int m = 0; m < 4; ++m){
#pragma unroll
        for (int n = 0; n < 4; ++n){
#pragma unroll
            for (int j = 0; j < 4; ++j){
                int rl = wm*64 + m*16 + (lane >> 4)*4 + j;
                int hc = h0 + wn*64 + n*16 + (lane & 15);
                atomicAdd(&out[(size_t)toks[rl] * HID + hc], acc[m][n][j]);
            }
        }
    }
}

extern "C" void kernel_launch(void* const* d_in, const int* in_sizes, int n_in,
                              void* d_out, int out_size, void* d_ws, size_t ws_size,
                              hipStream_t stream)
{
    const float* x  = (const float*)d_in[0];
    const float* gw = (const float*)d_in[1];
    const float* w1 = (const float*)d_in[2];
    const float* w3 = (const float*)d_in[3];
    const float* w2 = (const float*)d_in[4];
    float* out = (float*)d_out;

    char* ws = (char*)d_ws;
    size_t off = 0;
    auto bump = [&](size_t bytes) -> void* {
        void* p = ws + off;
        off = (off + bytes + 255) & ~(size_t)255;
        return p;
    };
    int*   counts     = (int*)bump(32);
    int*   cursors    = (int*)bump(32);
    int*   offp       = (int*)bump(64);
    int*   topk_idx   = (int*)bump((size_t)PAIRS * 4);
    float* topk_w     = (float*)bump((size_t)PAIRS * 4);
    int*   pair_token = (int*)bump((size_t)PAD_MAX * 4);
    float* pair_w     = (float*)bump((size_t)PAD_MAX * 4);
    unsigned short* xb  = (unsigned short*)bump((size_t)T_TOKENS * HID * 2);
    unsigned short* w1b = (unsigned short*)bump((size_t)NEXP * INTER * HID * 2);
    unsigned short* w3b = (unsigned short*)bump((size_t)NEXP * INTER * HID * 2);
    unsigned short* w2b = (unsigned short*)bump((size_t)NEXP * HID * INTER * 2);
    unsigned short* act = (unsigned short*)(ws + off);

    size_t rem = (ws_size > off) ? (ws_size - off) : 0;
    int RC = (int)(rem / ((size_t)INTER * 2));
    RC &= ~127;
    if (RC > PAD_MAX) RC = PAD_MAX;
    if (RC < 128) RC = 128;  // (ws proven >= 235 MB; this branch never taken)
    int nchunks = (PAD_MAX + RC - 1) / RC;

    hipMemsetAsync(d_out, 0, (size_t)T_TOKENS * HID * 4, stream);
    hipMemsetAsync(ws, 0, 1024, stream);

    conv_bf16_kernel<<<2048, 256, 0, stream>>>(x,  xb,  T_TOKENS * HID);
    conv_bf16_kernel<<<2048, 256, 0, stream>>>(w1, w1b, NEXP * INTER * HID);
    conv_bf16_kernel<<<2048, 256, 0, stream>>>(w3, w3b, NEXP * INTER * HID);
    conv_bf16_kernel<<<2048, 256, 0, stream>>>(w2, w2b, NEXP * HID * INTER);

    router_kernel<<<T_TOKENS/4, 256, 0, stream>>>(x, gw, topk_idx, topk_w, counts);
    scan_kernel<<<1, 64, 0, stream>>>(counts, offp);
    padfill_kernel<<<NEXP, 128, 0, stream>>>(counts, offp, pair_token, pair_w);
    scatter_kernel<<<T_TOKENS/256, 256, 0, stream>>>(topk_idx, topk_w, offp, cursors,
                                                     pair_token, pair_w);

    for (int c = 0; c < nchunks; ++c){
        int r0 = c * RC;
        gemm_act_kernel<<<dim3(INTER/64, RC/128), 256, 0, stream>>>(
            xb, w1b, w3b, offp, pair_token, pair_w, act, r0);
        gemm2_kernel<<<dim3(HID/128, RC/128), 256, 0, stream>>>(
            act, w2b, offp, pair_token, out, r0);
    }
}

// Round 3
// 1659.448 us; speedup vs baseline: 1.2455x; 1.1700x over previous
//
#include <hip/hip_runtime.h>
#include <hip/hip_bf16.h>

#define T_TOKENS 16384
#define HID 1024
#define NEXP 8
#define INTER 3584
#define PAIRS (2*T_TOKENS)
#define PAD_MAX (PAIRS + NEXP*128)   // 33792, multiple of 128

using f32x4    = __attribute__((ext_vector_type(4))) float;
using bfrag    = __attribute__((ext_vector_type(8))) short;
using float4_t = __attribute__((ext_vector_type(4))) float;
using ushort8_t = __attribute__((ext_vector_type(8))) unsigned short;

__device__ inline unsigned short f2bf(float f){
    unsigned u = __float_as_uint(f);
    u += 0x7FFFu + ((u >> 16) & 1u);          // RNE
    return (unsigned short)(u >> 16);
}

// async global -> LDS, 16B per lane, dest = ldsbase + lane*16 (linear)
__device__ inline void gload16(const unsigned short* g, unsigned short* l){
    __builtin_amdgcn_global_load_lds(
        (const __attribute__((address_space(1))) void*)g,
        (__attribute__((address_space(3))) void*)l, 16, 0, 0);
}

// bijective XCD swizzle (m204): contiguous grid chunk per XCD
__device__ inline int xcd_swz(int flat, int nwg){
    int q = nwg >> 3, r = nwg & 7;
    int xcd = flat & 7, idx = flat >> 3;
    return (xcd < r ? xcd*(q+1) : r*(q+1) + (xcd - r)*q) + idx;
}

// ---------------- f32 -> bf16 bulk conversion ----------------
__global__ __launch_bounds__(256) void conv_bf16_kernel(
    const float* __restrict__ in, unsigned short* __restrict__ out, int n)
{
    int i0 = (blockIdx.x * 256 + threadIdx.x) * 8;
    int stride = gridDim.x * 256 * 8;
    for (int i = i0; i < n; i += stride){
        float4_t a = *reinterpret_cast<const float4_t*>(in + i);
        float4_t b = *reinterpret_cast<const float4_t*>(in + i + 4);
        ushort8_t o;
        o[0]=f2bf(a.x); o[1]=f2bf(a.y); o[2]=f2bf(a.z); o[3]=f2bf(a.w);
        o[4]=f2bf(b.x); o[5]=f2bf(b.y); o[6]=f2bf(b.z); o[7]=f2bf(b.w);
        *reinterpret_cast<ushort8_t*>(out + i) = o;
    }
}

// ---------------- router ----------------
__global__ __launch_bounds__(256) void router_kernel(
    const float* __restrict__ x, const float* __restrict__ gw,
    int* __restrict__ topk_idx, float* __restrict__ topk_w,
    int* __restrict__ counts)
{
    int wave = threadIdx.x >> 6;
    int lane = threadIdx.x & 63;
    int t = blockIdx.x * 4 + wave;

    float acc[NEXP];
#pragma unroll
    for (int e = 0; e < NEXP; ++e) acc[e] = 0.f;

    const float* xr = x + (size_t)t * HID;
    for (int hb = 0; hb < HID; hb += 64){
        float xv = xr[hb + lane];
#pragma unroll
        for (int e = 0; e < NEXP; ++e)
            acc[e] += xv * gw[e * HID + hb + lane];
    }
#pragma unroll
    for (int e = 0; e < NEXP; ++e){
#pragma unroll
        for (int s = 32; s > 0; s >>= 1)
            acc[e] += __shfl_xor(acc[e], s, 64);
    }
    if (lane == 0){
        int e0 = 0; float m0 = acc[0];
#pragma unroll
        for (int e = 1; e < NEXP; ++e) if (acc[e] > m0){ m0 = acc[e]; e0 = e; }
        int e1 = -1; float m1 = -1e30f;
#pragma unroll
        for (int e = 0; e < NEXP; ++e) if (e != e0 && acc[e] > m1){ m1 = acc[e]; e1 = e; }
        float p1 = __expf(m1 - m0);
        float inv = 1.f / (1.f + p1);
        topk_idx[2*t]   = e0;
        topk_idx[2*t+1] = e1;
        topk_w[2*t]   = inv;
        topk_w[2*t+1] = p1 * inv;
        atomicAdd(&counts[e0], 1);
        atomicAdd(&counts[e1], 1);
    }
}

// ---------------- prefix scan with 128-row padding ----------------
__global__ void scan_kernel(const int* __restrict__ counts, int* __restrict__ offp)
{
    if (threadIdx.x == 0 && blockIdx.x == 0){
        int s = 0;
        for (int e = 0; e < NEXP; ++e){
            offp[e] = s;
            s += (counts[e] + 127) & ~127;
        }
        offp[NEXP] = s;
    }
}

__global__ __launch_bounds__(128) void padfill_kernel(
    const int* __restrict__ counts, const int* __restrict__ offp,
    int* __restrict__ pair_token, float* __restrict__ pair_w)
{
    int e = blockIdx.x;
    int base = offp[e];
    int aligned = offp[e+1] - base;
    for (int s = counts[e] + threadIdx.x; s < aligned; s += 128){
        pair_token[base + s] = (base + s) & (T_TOKENS - 1);
        pair_w[base + s] = 0.f;
    }
}

__global__ __launch_bounds__(256) void scatter_kernel(
    const int* __restrict__ topk_idx, const float* __restrict__ topk_w,
    const int* __restrict__ offp, int* __restrict__ cursors,
    int* __restrict__ pair_token, float* __restrict__ pair_w)
{
    int t = blockIdx.x * 256 + threadIdx.x;
#pragma unroll
    for (int k = 0; k < 2; ++k){
        int e = topk_idx[2*t + k];
        int slot = atomicAdd(&cursors[e], 1);
        int p = offp[e] + slot;
        pair_token[p] = t;
        pair_w[p] = topk_w[2*t + k];
    }
}

// ---------------- fused w1/w3 GEMM + SwiGLU -> act (bf16) ----------------
// M 128 x N 64 (h & u), BK=64, double-buffered, swizzled LDS
__global__ __launch_bounds__(256) void gemm_act_kernel(
    const unsigned short* __restrict__ xb,
    const unsigned short* __restrict__ w1b,
    const unsigned short* __restrict__ w3b,
    const int* __restrict__ offp,
    const int* __restrict__ pair_token, const float* __restrict__ pair_w,
    unsigned short* __restrict__ act, int r0)
{
    int nX = gridDim.x, nY = gridDim.y;
    int sw = xcd_swz(blockIdx.y * nX + blockIdx.x, nX * nY);
    int bx = sw / nY;          // N-panel major: same panel contiguous per XCD
    int by = sw % nY;

    int R = r0 + by * 128;
    if (R >= offp[NEXP]) return;
    int e = 0;
    while (offp[e+1] <= R) ++e;
    int icol0 = bx * 64;

    __shared__ alignas(16) unsigned short As0[128*64], As1[128*64];
    __shared__ alignas(16) unsigned short B10[64*64],  B11[64*64];
    __shared__ alignas(16) unsigned short B30[64*64],  B31[64*64];
    __shared__ int   toks[128];
    __shared__ float pws[128];

    int tid = threadIdx.x;
    if (tid < 128){
        toks[tid] = pair_token[R + tid];
        pws[tid]  = pair_w[R + tid];
    }
    __syncthreads();

    int w = tid >> 6, lane = tid & 63;
    int wm = w >> 1, wn = w & 1;
    int lr = lane >> 3;
    int l15 = lane & 15;
    int swz8 = ((lane & 7) ^ lr) * 8;          // inverse-swizzled source chunk

    size_t asrc[4];
#pragma unroll
    for (int i = 0; i < 4; ++i)
        asrc[i] = (size_t)toks[w*32 + i*8 + lr] * HID + swz8;

    const unsigned short* w1e = w1b + (size_t)e * INTER * HID;
    const unsigned short* w3e = w3b + (size_t)e * INTER * HID;
    size_t bsrc[2];
#pragma unroll
    for (int i = 0; i < 2; ++i)
        bsrc[i] = (size_t)(icol0 + w*16 + i*8 + lr) * HID + swz8;

    // swizzled read columns (shorts): ((kk*4 + lane>>4) ^ (row&7)) * 8, row&7 == lane&7
    int ccol[2];
#pragma unroll
    for (int kk = 0; kk < 2; ++kk)
        ccol[kk] = (((kk*4 + (lane >> 4)) ^ (lane & 7)) * 8);

    f32x4 acc_h[4][2], acc_u[4][2];
#pragma unroll
    for (int m = 0; m < 4; ++m)
#pragma unroll
        for (int n = 0; n < 2; ++n){
            acc_h[m][n] = (f32x4){0.f,0.f,0.f,0.f};
            acc_u[m][n] = (f32x4){0.f,0.f,0.f,0.f};
        }

    auto stageT = [&](unsigned short* As, unsigned short* B1s, unsigned short* B3s, int k0){
#pragma unroll
        for (int i = 0; i < 4; ++i) gload16(xb  + asrc[i] + k0, As  + (w*32 + i*8)*64);
#pragma unroll
        for (int i = 0; i < 2; ++i) gload16(w1e + bsrc[i] + k0, B1s + (w*16 + i*8)*64);
#pragma unroll
        for (int i = 0; i < 2; ++i) gload16(w3e + bsrc[i] + k0, B3s + (w*16 + i*8)*64);
    };

    auto computeT = [&](const unsigned short* As, const unsigned short* B1s, const unsigned short* B3s){
        __builtin_amdgcn_s_setprio(1);
#pragma unroll
        for (int kk = 0; kk < 2; ++kk){
            int cc = ccol[kk];
            bfrag a[4];
#pragma unroll
            for (int m = 0; m < 4; ++m)
                a[m] = *reinterpret_cast<const bfrag*>(&As[(wm*64 + m*16 + l15)*64 + cc]);
#pragma unroll
            for (int n = 0; n < 2; ++n){
                bfrag b1 = *reinterpret_cast<const bfrag*>(&B1s[(wn*32 + n*16 + l15)*64 + cc]);
                bfrag b3 = *reinterpret_cast<const bfrag*>(&B3s[(wn*32 + n*16 + l15)*64 + cc]);
#pragma unroll
                for (int m = 0; m < 4; ++m){
                    acc_h[m][n] = __builtin_amdgcn_mfma_f32_16x16x32_bf16(a[m], b1, acc_h[m][n], 0, 0, 0);
                    acc_u[m][n] = __builtin_amdgcn_mfma_f32_16x16x32_bf16(a[m], b3, acc_u[m][n], 0, 0, 0);
                }
            }
        }
        __builtin_amdgcn_s_setprio(0);
    };

    stageT(As0, B10, B30, 0);
    __syncthreads();
#pragma unroll 1
    for (int t = 0; t < HID/64; t += 2){
        if (t + 1 < HID/64) stageT(As1, B11, B31, (t+1)*64);
        computeT(As0, B10, B30);
        __syncthreads();
        if (t + 2 < HID/64) stageT(As0, B10, B30, (t+2)*64);
        computeT(As1, B11, B31);
        __syncthreads();
    }

    size_t arow0 = (size_t)(by * 128) * INTER;
#pragma unroll
    for (int m = 0; m < 4; ++m){
#pragma unroll
        for (int n = 0; n < 2; ++n){
#pragma unroll
            for (int j = 0; j < 4; ++j){
                int rl = wm*64 + m*16 + (lane >> 4)*4 + j;
                float h = acc_h[m][n][j];
                float u = acc_u[m][n][j];
                float v = pws[rl] * h * u / (1.f + __expf(-h));
                int ic = icol0 + wn*32 + n*16 + l15;
                act[arow0 + (size_t)rl * INTER + ic] = f2bf(v);
            }
        }
    }
}

// ---------------- down-proj GEMM: out[tok,:] += act[row,:] @ w2[e]^T ----------------
// M 128 x N 128, BK=64, K=INTER, double-buffered, swizzled LDS
__global__ __launch_bounds__(256) void gemm2_kernel(
    const unsigned short* __restrict__ act,
    const unsigned short* __restrict__ w2b,
    const int* __restrict__ offp,
    const int* __restrict__ pair_token,
    float* __restrict__ out, int r0)
{
    int nX = gridDim.x, nY = gridDim.y;
    int sw = xcd_swz(blockIdx.y * nX + blockIdx.x, nX * nY);
    int bx = sw / nY;
    int by = sw % nY;

    int R = r0 + by * 128;
    if (R >= offp[NEXP]) return;
    int e = 0;
    while (offp[e+1] <= R) ++e;
    int h0 = bx * 128;

    __shared__ alignas(16) unsigned short As0[128*64], As1[128*64];
    __shared__ alignas(16) unsigned short Bs0[128*64], Bs1[128*64];
    __shared__ int toks[128];

    int tid = threadIdx.x;
    if (tid < 128) toks[tid] = pair_token[R + tid];
    __syncthreads();

    int w = tid >> 6, lane = tid & 63;
    int wm = w >> 1, wn = w & 1;
    int lr = lane >> 3;
    int l15 = lane & 15;
    int swz8 = ((lane & 7) ^ lr) * 8;

    const unsigned short* w2e = w2b + (size_t)e * HID * INTER;
    size_t arow0 = (size_t)(by * 128) * INTER;

    size_t asrc[4], bsrc[4];
#pragma unroll
    for (int i = 0; i < 4; ++i){
        asrc[i] = arow0 + (size_t)(w*32 + i*8 + lr) * INTER + swz8;
        bsrc[i] = (size_t)(h0 + w*32 + i*8 + lr) * INTER + swz8;
    }

    int ccol[2];
#pragma unroll
    for (int kk = 0; kk < 2; ++kk)
        ccol[kk] = (((kk*4 + (lane >> 4)) ^ (lane & 7)) * 8);

    f32x4 acc[4][4];
#pragma unroll
    for (int m = 0; m < 4; ++m)
#pragma unroll
        for (int n = 0; n < 4; ++n)
            acc[m][n] = (f32x4){0.f,0.f,0.f,0.f};

    auto stageT = [&](unsigned short* As, unsigned short* Bs, int kc){
#pragma unroll
        for (int i = 0; i < 4; ++i) gload16(act + asrc[i] + kc, As + (w*32 + i*8)*64);
#pragma unroll
        for (int i = 0; i < 4; ++i) gload16(w2e + bsrc[i] + kc, Bs + (w*32 + i*8)*64);
    };

    auto computeT = [&](const unsigned short* As, const unsigned short* Bs){
        __builtin_amdgcn_s_setprio(1);
#pragma unroll
        for (int kk = 0; kk < 2; ++kk){
            int cc = ccol[kk];
            bfrag a[4];
#pragma unroll
            for (int m = 0; m < 4; ++m)
                a[m] = *reinterpret_cast<const bfrag*>(&As[(wm*64 + m*16 + l15)*64 + cc]);
#pragma unroll
            for (int n = 0; n < 4; ++n){
                bfrag b = *reinterpret_cast<const bfrag*>(&Bs[(wn*64 + n*16 + l15)*64 + cc]);
#pragma unroll
                for (int m = 0; m < 4; ++m)
                    acc[m][n] = __builtin_amdgcn_mfma_f32_16x16x32_bf16(a[m], b, acc[m][n], 0, 0, 0);
            }
        }
        __builtin_amdgcn_s_setprio(0);
    };

    stageT(As0, Bs0, 0);
    __syncthreads();
#pragma unroll 1
    for (int t = 0; t < INTER/64; t += 2){
        if (t + 1 < INTER/64) stageT(As1, Bs1, (t+1)*64);
        computeT(As0, Bs0);
        __syncthreads();
        if (t + 2 < INTER/64) stageT(As0, Bs0, (t+2)*64);
        computeT(As1, Bs1);
        __syncthreads();
    }

#pragma unroll
    for (int m = 0; m < 4; ++m){
#pragma unroll
        for (int n = 0; n < 4; ++n){
#pragma unroll
            for (int j = 0; j < 4; ++j){
                int rl = wm*64 + m*16 + (lane >> 4)*4 + j;
                int hc = h0 + wn*64 + n*16 + l15;
                atomicAdd(&out[(size_t)toks[rl] * HID + hc], acc[m][n][j]);
            }
        }
    }
}

extern "C" void kernel_launch(void* const* d_in, const int* in_sizes, int n_in,
                              void* d_out, int out_size, void* d_ws, size_t ws_size,
                              hipStream_t stream)
{
    const float* x  = (const float*)d_in[0];
    const float* gw = (const float*)d_in[1];
    const float* w1 = (const float*)d_in[2];
    const float* w3 = (const float*)d_in[3];
    const float* w2 = (const float*)d_in[4];
    float* out = (float*)d_out;

    char* ws = (char*)d_ws;
    size_t off = 0;
    auto bump = [&](size_t bytes) -> void* {
        void* p = ws + off;
        off = (off + bytes + 255) & ~(size_t)255;
        return p;
    };
    int*   counts     = (int*)bump(32);
    int*   cursors    = (int*)bump(32);
    int*   offp       = (int*)bump(64);
    int*   topk_idx   = (int*)bump((size_t)PAIRS * 4);
    float* topk_w     = (float*)bump((size_t)PAIRS * 4);
    int*   pair_token = (int*)bump((size_t)PAD_MAX * 4);
    float* pair_w     = (float*)bump((size_t)PAD_MAX * 4);
    unsigned short* xb  = (unsigned short*)bump((size_t)T_TOKENS * HID * 2);
    unsigned short* w1b = (unsigned short*)bump((size_t)NEXP * INTER * HID * 2);
    unsigned short* w3b = (unsigned short*)bump((size_t)NEXP * INTER * HID * 2);
    unsigned short* w2b = (unsigned short*)bump((size_t)NEXP * HID * INTER * 2);
    unsigned short* act = (unsigned short*)(ws + off);

    size_t rem = (ws_size > off) ? (ws_size - off) : 0;
    int RC = (int)(rem / ((size_t)INTER * 2));
    RC &= ~127;
    if (RC > PAD_MAX) RC = PAD_MAX;
    if (RC < 128) RC = 128;
    int nchunks = (PAD_MAX + RC - 1) / RC;

    hipMemsetAsync(d_out, 0, (size_t)T_TOKENS * HID * 4, stream);
    hipMemsetAsync(ws, 0, 1024, stream);

    conv_bf16_kernel<<<2048, 256, 0, stream>>>(x,  xb,  T_TOKENS * HID);
    conv_bf16_kernel<<<2048, 256, 0, stream>>>(w1, w1b, NEXP * INTER * HID);
    conv_bf16_kernel<<<2048, 256, 0, stream>>>(w3, w3b, NEXP * INTER * HID);
    conv_bf16_kernel<<<2048, 256, 0, stream>>>(w2, w2b, NEXP * HID * INTER);

    router_kernel<<<T_TOKENS/4, 256, 0, stream>>>(x, gw, topk_idx, topk_w, counts);
    scan_kernel<<<1, 64, 0, stream>>>(counts, offp);
    padfill_kernel<<<NEXP, 128, 0, stream>>>(counts, offp, pair_token, pair_w);
    scatter_kernel<<<T_TOKENS/256, 256, 0, stream>>>(topk_idx, topk_w, offp, cursors,
                                                     pair_token, pair_w);

    for (int c = 0; c < nchunks; ++c){
        int r0 = c * RC;
        gemm_act_kernel<<<dim3(INTER/64, RC/128), 256, 0, stream>>>(
            xb, w1b, w3b, offp, pair_token, pair_w, act, r0);
        gemm2_kernel<<<dim3(HID/128, RC/128), 256, 0, stream>>>(
            act, w2b, offp, pair_token, out, r0);
    }
}